// Round 8
// baseline (156.937 us; speedup 1.0000x reference)
//
#include <hip/hip_runtime.h>
#include <math.h>

#define IMG_H 512
#define IMG_W 512
#define NSLOT 64
#define HT_R  56          // hT row-dim stride in halves (48 used); col stride 112 B

typedef _Float16 f16x4 __attribute__((ext_vector_type(4)));
typedef _Float16 f16x8 __attribute__((ext_vector_type(8)));
typedef float    f32x4 __attribute__((ext_vector_type(4)));

__device__ __forceinline__ f16x8 pack8(const float4& a, const float4& b) {
    return f16x8{(_Float16)a.x, (_Float16)a.y, (_Float16)a.z, (_Float16)a.w,
                 (_Float16)b.x, (_Float16)b.y, (_Float16)b.z, (_Float16)b.w};
}

// Build one lane-fragment: Bw (which=0): w[k-ln-3]; A2w (which=1): w[k-ln]
__device__ __forceinline__ f16x8 build_frag(int which, int l)
{
    const int lln = l & 15, llg = l >> 4;
    f16x8 f;
    #pragma unroll
    for (int j = 0; j < 8; ++j) {
        int idx = llg * 8 + j - lln - (which ? 0 : 3);
        float d = (float)(idx - 5);
        float v = 0.26601173f * exp2f(-d * d * 0.32059889f);
        f[j] = (_Float16)(((unsigned)idx <= 10u) ? v : 0.0f);
    }
    return f;
}

__global__ void ssim_frag_init(f16x8* __restrict__ frags)
{
    const int tid = threadIdx.x;          // 128 threads
    if (tid < 128) frags[tid] = build_frag(tid >> 6, tid & 63);
}

__global__ __launch_bounds__(256, 6)
void ssim_main(const float* __restrict__ pred, const float* __restrict__ targ,
               const f16x8* __restrict__ frags, float* __restrict__ partial,
               double* __restrict__ acc, int mode)
{
    // [ct][q][col 0..15][row 0..47 (stride 56)] -- each wave reads only rows it wrote
    __shared__ _Float16 hT[2][5][16][HT_R];

    const int tid  = threadIdx.x;
    const int lane = tid & 63, wave = tid >> 6;
    const int ln   = lane & 15, lg = lane >> 4;
    const int ct   = wave >> 1, par = wave & 1;

    const int tx = blockIdx.x, ty = blockIdx.y, img = blockIdx.z;
    const float* __restrict__ p = pred + (size_t)img * (IMG_H * IMG_W);
    const float* __restrict__ t = targ + (size_t)img * (IMG_H * IMG_W);

    // ---- banded weight fragments (precomputed in ws; fallback: compute inline) ----
    f16x8 Bw, A2w;
    if (frags) { Bw = frags[lane]; A2w = frags[64 + lane]; }
    else       { Bw = build_frag(0, lane); A2w = build_frag(1, lane); }

    // ---- global loads: 2 row-positions, 8 floats/lane/img, 32B-aligned ----
    // halo col 0 = global col tx*32-8; lane covers halo cols ct*16+8lg .. +7
    const int rb0 = par ? 16 : 0;                    // even: rows {0,16}; odd: {16,32}
    const int gc  = tx * 32 + ct * 16 + lg * 8 - 8;
    const bool colOK = (gc >= 0) && (gc <= IMG_W - 8);
    float4 P[2][2] = {}, T[2][2] = {};
    #pragma unroll
    for (int pos = 0; pos < 2; ++pos) {
        const int gr = ty * 32 - 5 + rb0 + 16 * pos + ln;   // halo row = A row m=ln
        if (colOK && gr >= 0 && gr < IMG_H) {
            const float* bp = p + (size_t)gr * IMG_W + gc;
            const float* bt = t + (size_t)gr * IMG_W + gc;
            P[pos][0] = ((const float4*)bp)[0];  P[pos][1] = ((const float4*)bp)[1];
            T[pos][0] = ((const float4*)bt)[0];  T[pos][1] = ((const float4*)bt)[1];
        }
    }
    const f32x4 z = {0.f, 0.f, 0.f, 0.f};

    // ---- Stage B: horizontal conv via MFMA (wave-private; duplicates are bit-identical) ----
    #pragma unroll
    for (int pos = 0; pos < 2; ++pos) {
        const int rowbase = rb0 + 16 * pos;
        f16x8 pa = pack8(P[pos][0], P[pos][1]);
        f16x8 ta = pack8(T[pos][0], T[pos][1]);
        f16x8 fq[5];
        fq[0] = pa; fq[1] = ta;
        fq[2] = pa * pa; fq[3] = ta * ta; fq[4] = pa * ta;
        const int orow = rowbase + lg * 4;          // b64-aligned (rowbase mult of 16)
        #pragma unroll
        for (int q = 0; q < 5; ++q) {
            f32x4 d = __builtin_amdgcn_mfma_f32_16x16x32_f16(fq[q], Bw, z, 0, 0, 0);
            *(f16x4*)&hT[ct][q][ln][orow] =
                f16x4{(_Float16)d[0], (_Float16)d[1], (_Float16)d[2], (_Float16)d[3]};
        }
    }

    // ---- Stage C: vertical conv via MFMA -- reads ONLY this wave's hT rows ----
    // same-wave DS ops are in-order; no __syncthreads anywhere
    float lsum = 0.f;
    {
        const int rbase = par * 16 + lg * 8;        // 16B-aligned b128 reads
        f32x4 accq[5];
        #pragma unroll
        for (int q = 0; q < 5; ++q) {
            f16x8 b = *(const f16x8*)&hT[ct][q][ln][rbase];
            accq[q] = __builtin_amdgcn_mfma_f32_16x16x32_f16(A2w, b, z, 0, 0, 0);
        }
        const float C1 = 1e-4f, C2 = 9e-4f;
        #pragma unroll
        for (int r = 0; r < 4; ++r) {
            float mp = accq[0][r], mt = accq[1][r];
            float vp = accq[2][r] - mp * mp;
            float vt = accq[3][r] - mt * mt;
            float cv = accq[4][r] - mp * mt;
            float num = (2.f * mp * mt + C1) * (2.f * cv + C2);
            float den = (mp * mp + mt * mt + C1) * (vp + vt + C2);
            lsum = fmaf(num, __builtin_amdgcn_rcpf(den), lsum);
        }
    }

    // ---- wave reduce -> per-wave slot (mode 0) or atomic (mode 1) ----
    #pragma unroll
    for (int off = 32; off > 0; off >>= 1)
        lsum += __shfl_down(lsum, off, 64);
    if (lane == 0) {
        const int bid = (blockIdx.z * gridDim.y + blockIdx.y) * gridDim.x + blockIdx.x;
        if (mode == 0) partial[bid * 4 + wave] = lsum;
        else atomicAdd(&acc[(bid * 4 + wave) & (NSLOT - 1)], (double)lsum);
    }
}

__global__ void ssim_init(double* acc)
{
    if (threadIdx.x < NSLOT) acc[threadIdx.x] = 0.0;
}

__global__ __launch_bounds__(1024)
void ssim_fin_slots(const float* __restrict__ partial, float* __restrict__ out,
                    int n4, double inv_n)
{
    __shared__ double red[16];
    double s = 0.0;
    const int tid = threadIdx.x;
    for (int i = tid; i < n4; i += 1024) {
        float4 v = ((const float4*)partial)[i];
        s += (double)v.x + (double)v.y + (double)v.z + (double)v.w;
    }
    #pragma unroll
    for (int off = 32; off > 0; off >>= 1)
        s += __shfl_down(s, off, 64);
    if ((tid & 63) == 0) red[tid >> 6] = s;
    __syncthreads();
    if (tid == 0) {
        double tot = 0.0;
        #pragma unroll
        for (int w = 0; w < 16; ++w) tot += red[w];
        out[0] = (float)(1.0 - tot * inv_n);
    }
}

__global__ void ssim_fin_atomic(const double* __restrict__ acc, float* __restrict__ out,
                                double inv_n)
{
    if (threadIdx.x == 0) {
        double s = 0.0;
        for (int i = 0; i < NSLOT; ++i) s += acc[i];
        out[0] = (float)(1.0 - s * inv_n);
    }
}

extern "C" void kernel_launch(void* const* d_in, const int* in_sizes, int n_in,
                              void* d_out, int out_size, void* d_ws, size_t ws_size,
                              hipStream_t stream)
{
    const float* pred = (const float*)d_in[0];
    const float* targ = (const float*)d_in[1];
    float* out = (float*)d_out;

    const long long total = (long long)in_sizes[0];       // 16*3*512*512
    const int n_img = (int)(total / (IMG_H * IMG_W));     // 48 planes
    dim3 grid(IMG_W / 32, IMG_H / 32, n_img);
    const int nblk = grid.x * grid.y * grid.z;
    const int nslots = nblk * 4;
    const double inv_n = 1.0 / (double)total;
    const size_t fragBytes = 128 * sizeof(f16x8);         // 2 KB

    if (ws_size >= fragBytes + (size_t)nslots * sizeof(float)) {
        f16x8* frags   = (f16x8*)d_ws;
        float* partial = (float*)((char*)d_ws + fragBytes);
        hipLaunchKernelGGL(ssim_frag_init, dim3(1), dim3(128), 0, stream, frags);
        hipLaunchKernelGGL(ssim_main, grid, dim3(256), 0, stream,
                           pred, targ, (const f16x8*)frags, partial, (double*)nullptr, 0);
        hipLaunchKernelGGL(ssim_fin_slots, dim3(1), dim3(1024), 0, stream,
                           partial, out, nslots / 4, inv_n);
    } else {
        double* acc = (double*)d_ws;
        hipLaunchKernelGGL(ssim_init, dim3(1), dim3(64), 0, stream, acc);
        hipLaunchKernelGGL(ssim_main, grid, dim3(256), 0, stream,
                           pred, targ, (const f16x8*)nullptr, (float*)nullptr, acc, 1);
        hipLaunchKernelGGL(ssim_fin_atomic, dim3(1), dim3(1), 0, stream,
                           acc, out, inv_n);
    }
}